// Round 8
// baseline (132.175 us; speedup 1.0000x reference)
//
#include <hip/hip_runtime.h>

typedef __attribute__((ext_vector_type(8))) short bf16x8;
typedef __attribute__((ext_vector_type(4))) float f32x4;

#define NBATCH 16384
#define SS     300
#define AA     30
#define ROWS   16
#define SSTR   328     // 164 dw % 32 = 4 -> GEMM1 A-reads conflict-free
#define HSTR   280     // 140 dw % 32 = 12 -> conflict-free
#define K1P    320
#define SCALEF 0.0625f
#define ETA0   0.1f

__device__ __forceinline__ short f2b(float x) {
    unsigned u = __float_as_uint(x);
    unsigned r = (u + 0x7FFFu + ((u >> 16) & 1u)) >> 16;
    return (short)r;
}
__device__ __forceinline__ float b2f(short s) {
    return __uint_as_float(((unsigned)(unsigned short)s) << 16);
}
__device__ __forceinline__ float tanh_fast(float x) {
    float e = __expf(2.f * x);
    return 1.f - 2.f / (e + 1.f);
}

// ---------------------------------------------------------------------------
// Pre-kernel: round-6/7 version verbatim (best measured).
// ---------------------------------------------------------------------------
__global__ __launch_bounds__(256) void pre_kernel(
    const float* __restrict__ proto, const float* __restrict__ W1,
    const float* __restrict__ W2,   const float* __restrict__ b2,
    const float* __restrict__ tcW,  const float* __restrict__ cWp,
    const float* __restrict__ dW1,  const float* __restrict__ db1,
    const float* __restrict__ dW2,  const float* __restrict__ db2,
    short* __restrict__ W1P, short* __restrict__ W3P,
    short* __restrict__ PDP, short* __restrict__ TCP,
    float* __restrict__ cmn, float* __restrict__ conc)
{
    __shared__ short sbuf[64 * 264 + 4096];
    const int t = threadIdx.x;
    const int bid = blockIdx.x;

    if (bid < 32) {
        const int m = bid >> 2, jt = bid & 3;
        short* W2s = sbuf;
        short* prS = sbuf + 64 * 264;
        #pragma unroll 8
        for (int it = 0; it < 64; ++it) {
            const int idx = it * 256 + t, j = idx >> 8, e = idx & 255;
            W2s[j * 264 + e] = f2b(W2[(size_t)(jt * 64 + j) * 2048 + m * 256 + e]);
        }
        #pragma unroll 8
        for (int it = 0; it < 16; ++it) {
            const int id = it * 256 + t, chunk = id >> 3, j8 = id & 7;
            const int kt = chunk >> 6, rem = chunk & 63, q = rem >> 4, n = rem & 15;
            prS[id] = f2b(proto[n * 256 + kt * 32 + q * 8 + j8]);
        }
        __syncthreads();
        const int lane = t & 63, wv = t >> 6, l15 = lane & 15, q = lane >> 4;
        f32x4 acc = {0.f, 0.f, 0.f, 0.f};
        for (int kt = 0; kt < 8; ++kt) {
            bf16x8 a = *(const bf16x8*)&W2s[(wv * 16 + l15) * 264 + kt * 32 + q * 8];
            bf16x8 b = *(const bf16x8*)&prS[((kt * 4 + q) * 16 + l15) * 8];
            acc = __builtin_amdgcn_mfma_f32_16x16x32_bf16(a, b, acc, 0, 0, 0);
        }
        #pragma unroll
        for (int reg = 0; reg < 4; ++reg) {
            const int jg = jt * 64 + wv * 16 + q * 4 + reg;
            const int c = m * 16 + l15;
            const int ktj = jg >> 5, qj = (jg >> 3) & 3, j8 = jg & 7;
            W3P[((ktj * 4 + qj) * 128 + c) * 8 + j8] = f2b(acc[reg]);
        }
    } else if (bid < 42) {
        const int kt = bid - 32;
        short* W1s = sbuf;
        #pragma unroll 8
        for (int it = 0; it < 32; ++it) {
            const int idx = it * 256 + t, k = idx >> 8, n = idx & 255;
            const int kg = kt * 32 + k;
            W1s[k * 256 + n] = (kg < SS) ? f2b(W1[(size_t)kg * 256 + n]) : (short)0;
        }
        __syncthreads();
        #pragma unroll
        for (int it = 0; it < 4; ++it) {
            const int id = it * 256 + t, q = id >> 8, n = id & 255;
            bf16x8 v;
            #pragma unroll
            for (int j = 0; j < 8; ++j) v[j] = W1s[(q * 8 + j) * 256 + n];
            *(bf16x8*)&W1P[((kt * 4 + q) * 256 + n) * 8] = v;
        }
    } else if (bid == 42) {
        #pragma unroll 4
        for (int it = 0; it < 32; ++it) {
            const int id = it * 256 + t, chunk = id >> 3, j8 = id & 7;
            const int kt = chunk >> 7, q = (chunk >> 5) & 3, np = chunk & 31;
            const int k = kt * 32 + q * 8 + j8;
            float v = 0.f;
            if (np < 16) v = proto[np * 256 + k];
            else if (np == 16) v = cWp[k];
            PDP[id] = f2b(v);
        }
    } else if (bid == 43) {
        #pragma unroll 4
        for (int it = 0; it < 32; ++it) {
            const int id = it * 256 + t, chunk = id >> 3, j8 = id & 7;
            const int q = chunk >> 8, n = chunk & 255, k = q * 8 + j8;
            TCP[id] = (k < 12) ? f2b(tcW[k * 256 + n]) : (short)0;
        }
    } else if (bid == 44) {
        float* b2s = (float*)sbuf;
        float* prF = b2s + 2048;
        #pragma unroll
        for (int it = 0; it < 8; ++it)  b2s[it * 256 + t] = b2[it * 256 + t];
        #pragma unroll
        for (int it = 0; it < 16; ++it) prF[it * 256 + t] = proto[it * 256 + t];
        __syncthreads();
        if (t < 128) {
            const int mq = t >> 4, n = t & 15;
            float acc = 0.f;
            #pragma unroll 4
            for (int e = 0; e < 256; ++e) acc += b2s[mq * 256 + e] * prF[n * 256 + e];
            cmn[t] = acc;
        }
    } else {
        const int m = bid - 45;
        float* pr    = (float*)sbuf;
        float* hdp   = pr + 256;
        float* hdv   = hdp + 256;
        float* cpart = hdv + 128;
        pr[t] = proto[m * 256 + t];
        __syncthreads();
        {
            const int half = t >> 7, h = t & 127;
            const float* wp = dW1 + (size_t)m * 32768 + (size_t)half * 16384 + h;
            float a0 = 0.f, a1 = 0.f, a2 = 0.f, a3 = 0.f;
            #pragma unroll 8
            for (int e = 0; e < 128; e += 4) {
                const int eg = half * 128 + e;
                a0 = fmaf(pr[eg + 0], wp[(e + 0) * 128], a0);
                a1 = fmaf(pr[eg + 1], wp[(e + 1) * 128], a1);
                a2 = fmaf(pr[eg + 2], wp[(e + 2) * 128], a2);
                a3 = fmaf(pr[eg + 3], wp[(e + 3) * 128], a3);
            }
            hdp[half * 128 + h] = (a0 + a1) + (a2 + a3);
        }
        __syncthreads();
        if (t < 128) hdv[t] = fmaxf(hdp[t] + hdp[128 + t] + db1[m * 128 + t], 0.f);
        __syncthreads();
        {
            const int g = t >> 5, a = t & 31;
            float cacc = 0.f;
            if (a < AA) {
                const float* w2p = dW2 + (size_t)m * 128 * AA + g * 16 * AA + a;
                #pragma unroll
                for (int hh = 0; hh < 16; ++hh)
                    cacc = fmaf(hdv[g * 16 + hh], w2p[hh * AA], cacc);
            }
            cpart[g * 32 + a] = cacc;
        }
        __syncthreads();
        if (t < AA) {
            float s = db2[m * AA + t];
            #pragma unroll
            for (int g2 = 0; g2 < 8; ++g2) s += cpart[g2 * 32 + t];
            conc[m * AA + t] = fmaxf(s, 0.f) + log1pf(__expf(-fabsf(s)));
        }
    }
}

// ---------------------------------------------------------------------------
// Main kernel: r7 structure + in-register token softmax (no logits LDS
// round-trip; 8 barriers).
// ---------------------------------------------------------------------------
__global__ __launch_bounds__(256, 5) void main_kernel(
    const float* __restrict__ state, const float* __restrict__ fitness,
    const float* __restrict__ b1,
    const float* __restrict__ lng,  const float* __restrict__ lnb,
    const float* __restrict__ tcb,  const float* __restrict__ cb,
    const float* __restrict__ pw,
    const short* __restrict__ W1P,  const short* __restrict__ W3P,
    const short* __restrict__ PDP,  const short* __restrict__ TCP,
    const float* __restrict__ cmn,  const float* __restrict__ conc,
    float* __restrict__ out)
{
    const int t    = threadIdx.x;
    const int row0 = blockIdx.x * ROWS;
    const int w    = t >> 6;
    const int lane = t & 63;
    const int l15  = lane & 15;
    const int q    = lane >> 4;

    __shared__ short sA[ROWS * SSTR];
    __shared__ short sB[ROWS * HSTR];
    __shared__ short s_mfB[ROWS * 32];
    __shared__ float s_red[ROWS][8];
    __shared__ float s_dd[ROWS * 16];
    __shared__ float s_crisis[ROWS];
    __shared__ float s_cmn[128];
    __shared__ float s_conc[16 * AA];

    float* s_wrep = (float*)&sA[ROWS * HSTR];   // 16*16 fp32 at 8960 B (< 10496)
    float* s_part = (float*)sB;                 // [row][4 waves][16 n] after B4

    // ---- prefetch per-thread scalars needed late ----
    const float fit_pre = fitness[(size_t)(row0 + (t >> 4)) * 16 + (t & 15)];
    const float pw_pre  = pw[t & 15];

    // ---- P1: stage state bf16 via float4 + zero-pad + small tables ----
    #pragma unroll
    for (int it = 0; it < 5; ++it) {
        const int idx = it * 256 + t;
        if (idx < ROWS * 75) {
            const int r = idx / 75, c4 = idx - r * 75;
            const float4 v = *(const float4*)&state[(size_t)(row0 + r) * SS + c4 * 4];
            short4 s4;
            s4.x = f2b(v.x); s4.y = f2b(v.y); s4.z = f2b(v.z); s4.w = f2b(v.w);
            *(short4*)&sA[r * SSTR + c4 * 4] = s4;
        }
    }
    for (int i = t; i < ROWS * 20; i += 256) {
        const int r = i / 20, k = SS + i - r * 20;
        sA[r * SSTR + k] = 0;
    }
    for (int it = t; it < 128 + 16 * AA; it += 256) {
        if (it < 128) s_cmn[it] = cmn[it];
        else s_conc[it - 128] = conc[it - 128];
    }
    __syncthreads();   // B1

    // ---- P2: market features -> s_mfB bf16 ----
    {
        const int r = t >> 4, g = t & 15;
        float sp = 0.f, sp2 = 0.f, sps = 0.f;
        if (g < 15) {
            #pragma unroll
            for (int jj = 0; jj < 2; ++jj) {
                const int i = 2 * g + jj;
                const float p = b2f(sA[r * SSTR + 1 + i]);
                const float s = b2f(sA[r * SSTR + 31 + i]);
                sp += p; sp2 += p * p; sps += p * s;
            }
        }
        #pragma unroll
        for (int off = 1; off < 16; off <<= 1) {
            sp  += __shfl_xor(sp, off);
            sp2 += __shfl_xor(sp2, off);
            sps += __shfl_xor(sps, off);
        }
        if (g < 8) s_mfB[r * 32 + 4 + g] = sA[r * SSTR + 61 + 30 * g];
        for (int k = 12 + g; k < 32; k += 16) s_mfB[r * 32 + k] = 0;
        if (g == 0) {
            const float bal = b2f(sA[r * SSTR]);
            const float pm = sp * (1.f / 30.f);
            const float var = (sp2 - 30.f * pm * pm) * (1.f / 29.f);
            const float pstd = sqrtf(fmaxf(var, 0.f)) + 1e-8f;
            s_mfB[r * 32 + 0] = sA[r * SSTR];
            s_mfB[r * 32 + 1] = f2b(pm);
            s_mfB[r * 32 + 2] = f2b(pstd);
            s_mfB[r * 32 + 3] = f2b(bal / (bal + sps + 1e-8f));
        }
    }
    __syncthreads();   // B2

    // ---- P3+P5 fused: danger MFMA (-> sB) and GEMM1 MFMA (-> regs) ----
    f32x4 acc[4];
    {
        f32x4 dacc[4];
        #pragma unroll
        for (int u = 0; u < 4; ++u) dacc[u] = (f32x4){0.f, 0.f, 0.f, 0.f};
        bf16x8 amf = *(const bf16x8*)&s_mfB[l15 * 32 + q * 8];
        #pragma unroll
        for (int u = 0; u < 4; ++u) {
            bf16x8 b = *(const bf16x8*)&TCP[((q << 8) | (w * 64 + u * 16 + l15)) * 8];
            dacc[u] = __builtin_amdgcn_mfma_f32_16x16x32_bf16(amf, b, dacc[u], 0, 0, 0);
        }
        #pragma unroll
        for (int u = 0; u < 4; ++u) {
            const int col = w * 64 + u * 16 + l15;
            const float tb = tcb[col];
            #pragma unroll
            for (int reg = 0; reg < 4; ++reg)
                sB[(q * 4 + reg) * HSTR + col] = f2b(tanh_fast(dacc[u][reg] + tb));
        }
        #pragma unroll
        for (int u = 0; u < 4; ++u) acc[u] = (f32x4){0.f, 0.f, 0.f, 0.f};
        for (int kt = 0; kt < 10; ++kt) {
            bf16x8 a = *(const bf16x8*)&sA[l15 * SSTR + kt * 32 + q * 8];
            bf16x8 bfr[4];
            #pragma unroll
            for (int u = 0; u < 4; ++u)
                bfr[u] = *(const bf16x8*)&W1P[((kt * 4 + q) * 256 + (w * 64 + u * 16 + l15)) * 8];
            #pragma unroll
            for (int u = 0; u < 4; ++u)
                acc[u] = __builtin_amdgcn_mfma_f32_16x16x32_bf16(a, bfr[u], acc[u], 0, 0, 0);
        }
    }
    __syncthreads();   // B3

    // ---- P4+P6 fused: waves 0/1 ddot/crisis MFMA; all waves LN partials ----
    if (w == 0) {
        f32x4 ad = {0.f, 0.f, 0.f, 0.f};
        for (int kt = 0; kt < 8; ++kt) {
            bf16x8 a = *(const bf16x8*)&sB[l15 * HSTR + kt * 32 + q * 8];
            bf16x8 b = *(const bf16x8*)&PDP[((kt * 4 + q) * 32 + l15) * 8];
            ad = __builtin_amdgcn_mfma_f32_16x16x32_bf16(a, b, ad, 0, 0, 0);
        }
        #pragma unroll
        for (int reg = 0; reg < 4; ++reg)
            s_dd[(q * 4 + reg) * 16 + l15] = ad[reg];
    } else if (w == 1) {
        f32x4 ad = {0.f, 0.f, 0.f, 0.f};
        for (int kt = 0; kt < 8; ++kt) {
            bf16x8 a = *(const bf16x8*)&sB[l15 * HSTR + kt * 32 + q * 8];
            bf16x8 b = *(const bf16x8*)&PDP[((kt * 4 + q) * 32 + 16 + l15) * 8];
            ad = __builtin_amdgcn_mfma_f32_16x16x32_bf16(a, b, ad, 0, 0, 0);
        }
        if (l15 == 0) {
            const float cbv = cb[0];
            #pragma unroll
            for (int reg = 0; reg < 4; ++reg)
                s_crisis[q * 4 + reg] = 1.f / (1.f + __expf(-(ad[reg] + cbv)));
        }
    }
    {
        float b1v[4];
        #pragma unroll
        for (int u = 0; u < 4; ++u) b1v[u] = b1[w * 64 + u * 16 + l15];
        #pragma unroll
        for (int reg = 0; reg < 4; ++reg) {
            float s = 0.f, s2 = 0.f;
            #pragma unroll
            for (int u = 0; u < 4; ++u) {
                const float v = acc[u][reg] + b1v[u];
                acc[u][reg] = v;
                s += v; s2 += v * v;
            }
            #pragma unroll
            for (int off = 1; off < 16; off <<= 1) {
                s  += __shfl_xor(s, off);
                s2 += __shfl_xor(s2, off);
            }
            if (l15 == 0) {
                const int row = q * 4 + reg;
                s_red[row][w * 2]     = s;
                s_red[row][w * 2 + 1] = s2;
            }
        }
    }
    __syncthreads();   // B4

    // ---- per-thread mu/rstd ----
    float muv[4], rsv[4];
    #pragma unroll
    for (int reg = 0; reg < 4; ++reg) {
        const int row = q * 4 + reg;
        float S = 0.f, S2 = 0.f;
        #pragma unroll
        for (int ww = 0; ww < 4; ++ww) { S += s_red[row][2 * ww]; S2 += s_red[row][2 * ww + 1]; }
        const float mu = S * (1.f / 256.f);
        const float var = S2 * (1.f / 256.f) - mu * mu;
        muv[reg] = mu; rsv[reg] = rsqrtf(var + 1e-5f);
    }

    // ---- P7: LN + relu -> h bf16 in sA (stride HSTR) ----
    {
        float gv[4], bv[4];
        #pragma unroll
        for (int u = 0; u < 4; ++u) {
            gv[u] = lng[w * 64 + u * 16 + l15];
            bv[u] = lnb[w * 64 + u * 16 + l15];
        }
        #pragma unroll
        for (int reg = 0; reg < 4; ++reg) {
            const int row = q * 4 + reg;
            #pragma unroll
            for (int u = 0; u < 4; ++u) {
                const int col = w * 64 + u * 16 + l15;
                const float v = fmaxf((acc[u][reg] - muv[reg]) * rsv[reg] * gv[u] + bv[u], 0.f);
                sA[row * HSTR + col] = f2b(v);
            }
        }
    }
    __syncthreads();   // B5

    // ---- P8: GEMM2' + in-register token softmax + w_ot partials ----
    // c2[0] lane l15 holds (row=q*4+reg, m=2w, n=l15); c2[1] holds m=2w+1.
    {
        f32x4 c2[2];
        c2[0] = (f32x4){0.f, 0.f, 0.f, 0.f};
        c2[1] = (f32x4){0.f, 0.f, 0.f, 0.f};
        for (int kt = 0; kt < 8; ++kt) {
            bf16x8 a = *(const bf16x8*)&sA[l15 * HSTR + kt * 32 + q * 8];
            bf16x8 b0 = *(const bf16x8*)&W3P[((kt * 4 + q) * 128 + w * 32 + l15) * 8];
            bf16x8 b1f = *(const bf16x8*)&W3P[((kt * 4 + q) * 128 + w * 32 + 16 + l15) * 8];
            c2[0] = __builtin_amdgcn_mfma_f32_16x16x32_bf16(a, b0, c2[0], 0, 0, 0);
            c2[1] = __builtin_amdgcn_mfma_f32_16x16x32_bf16(a, b1f, c2[1], 0, 0, 0);
        }
        const float cm0 = s_cmn[w * 32 + l15], cm1 = s_cmn[w * 32 + 16 + l15];
        #pragma unroll
        for (int reg = 0; reg < 4; ++reg) {
            const int row = q * 4 + reg;
            const float dd = s_dd[row * 16 + l15];
            const float l0 = SCALEF * (c2[0][reg] + cm0 + dd);
            const float l1 = SCALEF * (c2[1][reg] + cm1 + dd);
            float mx0 = l0, mx1 = l1;
            #pragma unroll
            for (int off = 1; off < 16; off <<= 1) {
                mx0 = fmaxf(mx0, __shfl_xor(mx0, off));
                mx1 = fmaxf(mx1, __shfl_xor(mx1, off));
            }
            const float p0 = __expf(l0 - mx0);
            const float p1 = __expf(l1 - mx1);
            float s0 = p0, s1 = p1;
            #pragma unroll
            for (int off = 1; off < 16; off <<= 1) {
                s0 += __shfl_xor(s0, off);
                s1 += __shfl_xor(s1, off);
            }
            s_part[row * 64 + w * 16 + l15] = p0 / s0 + p1 / s1;
        }
    }
    __syncthreads();   // B6

    // ---- P10: w_ot (into s_dd) + unnormalized w_rep ----
    {
        const int r = t >> 4, n = t & 15;
        const float* sp = s_part + r * 64 + n;
        s_dd[t] = ((sp[0] + sp[16]) + (sp[32] + sp[48])) * 0.125f;
        s_wrep[t] = pw_pre * __expf(ETA0 * fit_pre);
    }
    __syncthreads();   // B7

    // ---- P11: blend -> w (in s_dd) ----
    if (t < ROWS) {
        float srep = 0.f;
        #pragma unroll
        for (int n = 0; n < 16; ++n) srep += s_wrep[t * 16 + n];
        const float irep = 1.f / (srep + 1e-8f);
        const float alpha = 0.06f + 0.24f * (1.f - s_crisis[t]);
        float wn[16], sw = 0.f;
        #pragma unroll
        for (int n = 0; n < 16; ++n) {
            wn[n] = alpha * s_dd[t * 16 + n] + (1.f - alpha) * s_wrep[t * 16 + n] * irep;
            sw += wn[n];
        }
        const float isw = 1.f / (sw + 1e-8f);
        #pragma unroll
        for (int n = 0; n < 16; ++n) s_dd[t * 16 + n] = wn[n] * isw;
    }
    __syncthreads();   // B8

    // ---- P12: mixed = w@conc + 1, softmax(30), write ----
    {
        const int r = w * 4 + q;
        const int a0 = l15;
        const int a1 = a0 + 16;
        const bool v1 = a1 < AA;
        float wreg[16];
        #pragma unroll
        for (int n = 0; n < 16; ++n) wreg[n] = s_dd[r * 16 + n];
        float m0 = 1.f, m1 = 1.f;
        const int a1s = v1 ? a1 : 0;
        #pragma unroll
        for (int n = 0; n < 16; ++n) {
            m0 = fmaf(wreg[n], s_conc[n * AA + a0], m0);
            m1 = fmaf(wreg[n], s_conc[n * AA + a1s], m1);
        }
        float mx = v1 ? fmaxf(m0, m1) : m0;
        #pragma unroll
        for (int off = 1; off < 16; off <<= 1) mx = fmaxf(mx, __shfl_xor(mx, off));
        float e0 = __expf(m0 - mx);
        float e1 = v1 ? __expf(m1 - mx) : 0.f;
        float se = e0 + e1;
        #pragma unroll
        for (int off = 1; off < 16; off <<= 1) se += __shfl_xor(se, off);
        const float inv = 1.f / se;
        out[(size_t)(row0 + r) * AA + a0] = e0 * inv;
        if (v1) out[(size_t)(row0 + r) * AA + a1] = e1 * inv;
    }
}

extern "C" void kernel_launch(void* const* d_in, const int* in_sizes, int n_in,
                              void* d_out, int out_size, void* d_ws, size_t ws_size,
                              hipStream_t stream) {
    const float* state   = (const float*)d_in[0];
    const float* fitness = (const float*)d_in[1];
    const float* proto   = (const float*)d_in[2];
    const float* enc_W1  = (const float*)d_in[3];
    const float* enc_b1  = (const float*)d_in[4];
    const float* ln_g    = (const float*)d_in[5];
    const float* ln_b    = (const float*)d_in[6];
    const float* enc_W2  = (const float*)d_in[7];
    const float* enc_b2  = (const float*)d_in[8];
    const float* dec_W1  = (const float*)d_in[9];
    const float* dec_b1  = (const float*)d_in[10];
    const float* dec_W2  = (const float*)d_in[11];
    const float* dec_b2  = (const float*)d_in[12];
    const float* tc_W    = (const float*)d_in[13];
    const float* tc_b    = (const float*)d_in[14];
    const float* tc_cW   = (const float*)d_in[15];
    const float* tc_cb   = (const float*)d_in[16];
    const float* w_prev  = (const float*)d_in[19];
    float* out = (float*)d_out;

    short* W1P = (short*)d_ws;              // 81920 shorts
    short* W3P = W1P + 81920;               // 32768
    short* PDP = W3P + 32768;               // 8192
    short* TCP = PDP + 8192;                // 8192
    float* cmn  = (float*)(TCP + 8192);     // 128
    float* conc = cmn + 128;                // 480

    pre_kernel<<<61, 256, 0, stream>>>(proto, enc_W1, enc_W2, enc_b2,
                                       tc_W, tc_cW,
                                       dec_W1, dec_b1, dec_W2, dec_b2,
                                       W1P, W3P, PDP, TCP, cmn, conc);
    main_kernel<<<NBATCH / ROWS, 256, 0, stream>>>(state, fitness,
                                                   enc_b1, ln_g, ln_b,
                                                   tc_b, tc_cb, w_prev,
                                                   W1P, W3P, PDP, TCP, cmn, conc, out);
}

// Round 9
// 128.257 us; speedup vs baseline: 1.0305x; 1.0305x over previous
//
#include <hip/hip_runtime.h>

typedef __attribute__((ext_vector_type(8))) short bf16x8;
typedef __attribute__((ext_vector_type(4))) float f32x4;

#define NBATCH 16384
#define SS     300
#define AA     30
#define ROWS   16
#define SSTR   328     // 164 dw % 32 = 4 -> GEMM1 A-reads conflict-free
#define HSTR   280     // 140 dw % 32 = 12 -> conflict-free
#define LSTR   132
#define K1P    320
#define SCALEF 0.0625f
#define ETA0   0.1f

__device__ __forceinline__ short f2b(float x) {
    unsigned u = __float_as_uint(x);
    unsigned r = (u + 0x7FFFu + ((u >> 16) & 1u)) >> 16;
    return (short)r;
}
__device__ __forceinline__ float b2f(short s) {
    return __uint_as_float(((unsigned)(unsigned short)s) << 16);
}
__device__ __forceinline__ float tanh_fast(float x) {
    float e = __expf(2.f * x);
    return 1.f - 2.f / (e + 1.f);
}

// ---------------------------------------------------------------------------
// Pre-kernel: round-6 version verbatim (best measured).
// ---------------------------------------------------------------------------
__global__ __launch_bounds__(256) void pre_kernel(
    const float* __restrict__ proto, const float* __restrict__ W1,
    const float* __restrict__ W2,   const float* __restrict__ b2,
    const float* __restrict__ tcW,  const float* __restrict__ cWp,
    const float* __restrict__ dW1,  const float* __restrict__ db1,
    const float* __restrict__ dW2,  const float* __restrict__ db2,
    short* __restrict__ W1P, short* __restrict__ W3P,
    short* __restrict__ PDP, short* __restrict__ TCP,
    float* __restrict__ cmn, float* __restrict__ conc)
{
    __shared__ short sbuf[64 * 264 + 4096];
    const int t = threadIdx.x;
    const int bid = blockIdx.x;

    if (bid < 32) {
        const int m = bid >> 2, jt = bid & 3;
        short* W2s = sbuf;
        short* prS = sbuf + 64 * 264;
        #pragma unroll 8
        for (int it = 0; it < 64; ++it) {
            const int idx = it * 256 + t, j = idx >> 8, e = idx & 255;
            W2s[j * 264 + e] = f2b(W2[(size_t)(jt * 64 + j) * 2048 + m * 256 + e]);
        }
        #pragma unroll 8
        for (int it = 0; it < 16; ++it) {
            const int id = it * 256 + t, chunk = id >> 3, j8 = id & 7;
            const int kt = chunk >> 6, rem = chunk & 63, q = rem >> 4, n = rem & 15;
            prS[id] = f2b(proto[n * 256 + kt * 32 + q * 8 + j8]);
        }
        __syncthreads();
        const int lane = t & 63, wv = t >> 6, l15 = lane & 15, q = lane >> 4;
        f32x4 acc = {0.f, 0.f, 0.f, 0.f};
        for (int kt = 0; kt < 8; ++kt) {
            bf16x8 a = *(const bf16x8*)&W2s[(wv * 16 + l15) * 264 + kt * 32 + q * 8];
            bf16x8 b = *(const bf16x8*)&prS[((kt * 4 + q) * 16 + l15) * 8];
            acc = __builtin_amdgcn_mfma_f32_16x16x32_bf16(a, b, acc, 0, 0, 0);
        }
        #pragma unroll
        for (int reg = 0; reg < 4; ++reg) {
            const int jg = jt * 64 + wv * 16 + q * 4 + reg;
            const int c = m * 16 + l15;
            const int ktj = jg >> 5, qj = (jg >> 3) & 3, j8 = jg & 7;
            W3P[((ktj * 4 + qj) * 128 + c) * 8 + j8] = f2b(acc[reg]);
        }
    } else if (bid < 42) {
        const int kt = bid - 32;
        short* W1s = sbuf;
        #pragma unroll 8
        for (int it = 0; it < 32; ++it) {
            const int idx = it * 256 + t, k = idx >> 8, n = idx & 255;
            const int kg = kt * 32 + k;
            W1s[k * 256 + n] = (kg < SS) ? f2b(W1[(size_t)kg * 256 + n]) : (short)0;
        }
        __syncthreads();
        #pragma unroll
        for (int it = 0; it < 4; ++it) {
            const int id = it * 256 + t, q = id >> 8, n = id & 255;
            bf16x8 v;
            #pragma unroll
            for (int j = 0; j < 8; ++j) v[j] = W1s[(q * 8 + j) * 256 + n];
            *(bf16x8*)&W1P[((kt * 4 + q) * 256 + n) * 8] = v;
        }
    } else if (bid == 42) {
        #pragma unroll 4
        for (int it = 0; it < 32; ++it) {
            const int id = it * 256 + t, chunk = id >> 3, j8 = id & 7;
            const int kt = chunk >> 7, q = (chunk >> 5) & 3, np = chunk & 31;
            const int k = kt * 32 + q * 8 + j8;
            float v = 0.f;
            if (np < 16) v = proto[np * 256 + k];
            else if (np == 16) v = cWp[k];
            PDP[id] = f2b(v);
        }
    } else if (bid == 43) {
        #pragma unroll 4
        for (int it = 0; it < 32; ++it) {
            const int id = it * 256 + t, chunk = id >> 3, j8 = id & 7;
            const int q = chunk >> 8, n = chunk & 255, k = q * 8 + j8;
            TCP[id] = (k < 12) ? f2b(tcW[k * 256 + n]) : (short)0;
        }
    } else if (bid == 44) {
        float* b2s = (float*)sbuf;
        float* prF = b2s + 2048;
        #pragma unroll
        for (int it = 0; it < 8; ++it)  b2s[it * 256 + t] = b2[it * 256 + t];
        #pragma unroll
        for (int it = 0; it < 16; ++it) prF[it * 256 + t] = proto[it * 256 + t];
        __syncthreads();
        if (t < 128) {
            const int mq = t >> 4, n = t & 15;
            float acc = 0.f;
            #pragma unroll 4
            for (int e = 0; e < 256; ++e) acc += b2s[mq * 256 + e] * prF[n * 256 + e];
            cmn[t] = acc;
        }
    } else {
        const int m = bid - 45;
        float* pr    = (float*)sbuf;
        float* hdp   = pr + 256;
        float* hdv   = hdp + 256;
        float* cpart = hdv + 128;
        pr[t] = proto[m * 256 + t];
        __syncthreads();
        {
            const int half = t >> 7, h = t & 127;
            const float* wp = dW1 + (size_t)m * 32768 + (size_t)half * 16384 + h;
            float a0 = 0.f, a1 = 0.f, a2 = 0.f, a3 = 0.f;
            #pragma unroll 8
            for (int e = 0; e < 128; e += 4) {
                const int eg = half * 128 + e;
                a0 = fmaf(pr[eg + 0], wp[(e + 0) * 128], a0);
                a1 = fmaf(pr[eg + 1], wp[(e + 1) * 128], a1);
                a2 = fmaf(pr[eg + 2], wp[(e + 2) * 128], a2);
                a3 = fmaf(pr[eg + 3], wp[(e + 3) * 128], a3);
            }
            hdp[half * 128 + h] = (a0 + a1) + (a2 + a3);
        }
        __syncthreads();
        if (t < 128) hdv[t] = fmaxf(hdp[t] + hdp[128 + t] + db1[m * 128 + t], 0.f);
        __syncthreads();
        {
            const int g = t >> 5, a = t & 31;
            float cacc = 0.f;
            if (a < AA) {
                const float* w2p = dW2 + (size_t)m * 128 * AA + g * 16 * AA + a;
                #pragma unroll
                for (int hh = 0; hh < 16; ++hh)
                    cacc = fmaf(hdv[g * 16 + hh], w2p[hh * AA], cacc);
            }
            cpart[g * 32 + a] = cacc;
        }
        __syncthreads();
        if (t < AA) {
            float s = db2[m * AA + t];
            #pragma unroll
            for (int g2 = 0; g2 < 8; ++g2) s += cpart[g2 * 32 + t];
            conc[m * AA + t] = fmaxf(s, 0.f) + log1pf(__expf(-fabsf(s)));
        }
    }
}

// ---------------------------------------------------------------------------
// Main kernel: round-7 version verbatim (best measured: 128.77 us total).
// ---------------------------------------------------------------------------
__global__ __launch_bounds__(256, 5) void main_kernel(
    const float* __restrict__ state, const float* __restrict__ fitness,
    const float* __restrict__ b1,
    const float* __restrict__ lng,  const float* __restrict__ lnb,
    const float* __restrict__ tcb,  const float* __restrict__ cb,
    const float* __restrict__ pw,
    const short* __restrict__ W1P,  const short* __restrict__ W3P,
    const short* __restrict__ PDP,  const short* __restrict__ TCP,
    const float* __restrict__ cmn,  const float* __restrict__ conc,
    float* __restrict__ out)
{
    const int t    = threadIdx.x;
    const int row0 = blockIdx.x * ROWS;
    const int w    = t >> 6;
    const int lane = t & 63;
    const int l15  = lane & 15;
    const int q    = lane >> 4;

    __shared__ short sA[ROWS * SSTR];
    __shared__ short sB[ROWS * HSTR];
    __shared__ short s_mfB[ROWS * 32];
    __shared__ float s_red[ROWS][8];
    __shared__ float s_dd[ROWS * 16];
    __shared__ float s_crisis[ROWS];
    __shared__ float s_cmn[128];
    __shared__ float s_conc[16 * AA];

    float* s_log  = (float*)sB;
    float* s_wrep = (float*)&sA[ROWS * HSTR];

    const float fit_pre = fitness[(size_t)(row0 + (t >> 4)) * 16 + (t & 15)];
    const float pw_pre  = pw[t & 15];

    // ---- P1: stage state bf16 via float4 + zero-pad + small tables ----
    #pragma unroll
    for (int it = 0; it < 5; ++it) {
        const int idx = it * 256 + t;
        if (idx < ROWS * 75) {
            const int r = idx / 75, c4 = idx - r * 75;
            const float4 v = *(const float4*)&state[(size_t)(row0 + r) * SS + c4 * 4];
            short4 s4;
            s4.x = f2b(v.x); s4.y = f2b(v.y); s4.z = f2b(v.z); s4.w = f2b(v.w);
            *(short4*)&sA[r * SSTR + c4 * 4] = s4;
        }
    }
    for (int i = t; i < ROWS * 20; i += 256) {
        const int r = i / 20, k = SS + i - r * 20;
        sA[r * SSTR + k] = 0;
    }
    for (int it = t; it < 128 + 16 * AA; it += 256) {
        if (it < 128) s_cmn[it] = cmn[it];
        else s_conc[it - 128] = conc[it - 128];
    }
    __syncthreads();   // B1

    // ---- P2: market features -> s_mfB bf16 ----
    {
        const int r = t >> 4, g = t & 15;
        float sp = 0.f, sp2 = 0.f, sps = 0.f;
        if (g < 15) {
            #pragma unroll
            for (int jj = 0; jj < 2; ++jj) {
                const int i = 2 * g + jj;
                const float p = b2f(sA[r * SSTR + 1 + i]);
                const float s = b2f(sA[r * SSTR + 31 + i]);
                sp += p; sp2 += p * p; sps += p * s;
            }
        }
        #pragma unroll
        for (int off = 1; off < 16; off <<= 1) {
            sp  += __shfl_xor(sp, off);
            sp2 += __shfl_xor(sp2, off);
            sps += __shfl_xor(sps, off);
        }
        if (g < 8) s_mfB[r * 32 + 4 + g] = sA[r * SSTR + 61 + 30 * g];
        for (int k = 12 + g; k < 32; k += 16) s_mfB[r * 32 + k] = 0;
        if (g == 0) {
            const float bal = b2f(sA[r * SSTR]);
            const float pm = sp * (1.f / 30.f);
            const float var = (sp2 - 30.f * pm * pm) * (1.f / 29.f);
            const float pstd = sqrtf(fmaxf(var, 0.f)) + 1e-8f;
            s_mfB[r * 32 + 0] = sA[r * SSTR];
            s_mfB[r * 32 + 1] = f2b(pm);
            s_mfB[r * 32 + 2] = f2b(pstd);
            s_mfB[r * 32 + 3] = f2b(bal / (bal + sps + 1e-8f));
        }
    }
    __syncthreads();   // B2

    // ---- P3+P5 fused: danger MFMA (-> sB) and GEMM1 MFMA (-> regs) ----
    f32x4 acc[4];
    {
        f32x4 dacc[4];
        #pragma unroll
        for (int u = 0; u < 4; ++u) dacc[u] = (f32x4){0.f, 0.f, 0.f, 0.f};
        bf16x8 amf = *(const bf16x8*)&s_mfB[l15 * 32 + q * 8];
        #pragma unroll
        for (int u = 0; u < 4; ++u) {
            bf16x8 b = *(const bf16x8*)&TCP[((q << 8) | (w * 64 + u * 16 + l15)) * 8];
            dacc[u] = __builtin_amdgcn_mfma_f32_16x16x32_bf16(amf, b, dacc[u], 0, 0, 0);
        }
        #pragma unroll
        for (int u = 0; u < 4; ++u) {
            const int col = w * 64 + u * 16 + l15;
            const float tb = tcb[col];
            #pragma unroll
            for (int reg = 0; reg < 4; ++reg)
                sB[(q * 4 + reg) * HSTR + col] = f2b(tanh_fast(dacc[u][reg] + tb));
        }
        #pragma unroll
        for (int u = 0; u < 4; ++u) acc[u] = (f32x4){0.f, 0.f, 0.f, 0.f};
        for (int kt = 0; kt < 10; ++kt) {
            bf16x8 a = *(const bf16x8*)&sA[l15 * SSTR + kt * 32 + q * 8];
            bf16x8 bfr[4];
            #pragma unroll
            for (int u = 0; u < 4; ++u)
                bfr[u] = *(const bf16x8*)&W1P[((kt * 4 + q) * 256 + (w * 64 + u * 16 + l15)) * 8];
            #pragma unroll
            for (int u = 0; u < 4; ++u)
                acc[u] = __builtin_amdgcn_mfma_f32_16x16x32_bf16(a, bfr[u], acc[u], 0, 0, 0);
        }
    }
    __syncthreads();   // B3

    // ---- P4+P6 fused: waves 0/1 ddot/crisis MFMA; all waves LN partials ----
    if (w == 0) {
        f32x4 ad = {0.f, 0.f, 0.f, 0.f};
        for (int kt = 0; kt < 8; ++kt) {
            bf16x8 a = *(const bf16x8*)&sB[l15 * HSTR + kt * 32 + q * 8];
            bf16x8 b = *(const bf16x8*)&PDP[((kt * 4 + q) * 32 + l15) * 8];
            ad = __builtin_amdgcn_mfma_f32_16x16x32_bf16(a, b, ad, 0, 0, 0);
        }
        #pragma unroll
        for (int reg = 0; reg < 4; ++reg)
            s_dd[(q * 4 + reg) * 16 + l15] = ad[reg];
    } else if (w == 1) {
        f32x4 ad = {0.f, 0.f, 0.f, 0.f};
        for (int kt = 0; kt < 8; ++kt) {
            bf16x8 a = *(const bf16x8*)&sB[l15 * HSTR + kt * 32 + q * 8];
            bf16x8 b = *(const bf16x8*)&PDP[((kt * 4 + q) * 32 + 16 + l15) * 8];
            ad = __builtin_amdgcn_mfma_f32_16x16x32_bf16(a, b, ad, 0, 0, 0);
        }
        if (l15 == 0) {
            const float cbv = cb[0];
            #pragma unroll
            for (int reg = 0; reg < 4; ++reg)
                s_crisis[q * 4 + reg] = 1.f / (1.f + __expf(-(ad[reg] + cbv)));
        }
    }
    {
        float b1v[4];
        #pragma unroll
        for (int u = 0; u < 4; ++u) b1v[u] = b1[w * 64 + u * 16 + l15];
        #pragma unroll
        for (int reg = 0; reg < 4; ++reg) {
            float s = 0.f, s2 = 0.f;
            #pragma unroll
            for (int u = 0; u < 4; ++u) {
                const float v = acc[u][reg] + b1v[u];
                acc[u][reg] = v;
                s += v; s2 += v * v;
            }
            #pragma unroll
            for (int off = 1; off < 16; off <<= 1) {
                s  += __shfl_xor(s, off);
                s2 += __shfl_xor(s2, off);
            }
            if (l15 == 0) {
                const int row = q * 4 + reg;
                s_red[row][w * 2]     = s;
                s_red[row][w * 2 + 1] = s2;
            }
        }
    }
    __syncthreads();   // B4

    // ---- per-thread mu/rstd ----
    float muv[4], rsv[4];
    #pragma unroll
    for (int reg = 0; reg < 4; ++reg) {
        const int row = q * 4 + reg;
        float S = 0.f, S2 = 0.f;
        #pragma unroll
        for (int ww = 0; ww < 4; ++ww) { S += s_red[row][2 * ww]; S2 += s_red[row][2 * ww + 1]; }
        const float mu = S * (1.f / 256.f);
        const float var = S2 * (1.f / 256.f) - mu * mu;
        muv[reg] = mu; rsv[reg] = rsqrtf(var + 1e-5f);
    }

    // ---- P7: LN + relu -> h bf16 in sA (stride HSTR) ----
    {
        float gv[4], bv[4];
        #pragma unroll
        for (int u = 0; u < 4; ++u) {
            gv[u] = lng[w * 64 + u * 16 + l15];
            bv[u] = lnb[w * 64 + u * 16 + l15];
        }
        #pragma unroll
        for (int reg = 0; reg < 4; ++reg) {
            const int row = q * 4 + reg;
            #pragma unroll
            for (int u = 0; u < 4; ++u) {
                const int col = w * 64 + u * 16 + l15;
                const float v = fmaxf((acc[u][reg] - muv[reg]) * rsv[reg] * gv[u] + bv[u], 0.f);
                sA[row * HSTR + col] = f2b(v);
            }
        }
    }
    __syncthreads();   // B5

    // ---- P8: GEMM2' logits = SCALE*(h @ W3 + cmn + ddot) ----
    {
        f32x4 c2[2];
        c2[0] = (f32x4){0.f, 0.f, 0.f, 0.f};
        c2[1] = (f32x4){0.f, 0.f, 0.f, 0.f};
        for (int kt = 0; kt < 8; ++kt) {
            bf16x8 a = *(const bf16x8*)&sA[l15 * HSTR + kt * 32 + q * 8];
            bf16x8 b0 = *(const bf16x8*)&W3P[((kt * 4 + q) * 128 + w * 32 + l15) * 8];
            bf16x8 b1f = *(const bf16x8*)&W3P[((kt * 4 + q) * 128 + w * 32 + 16 + l15) * 8];
            c2[0] = __builtin_amdgcn_mfma_f32_16x16x32_bf16(a, b0, c2[0], 0, 0, 0);
            c2[1] = __builtin_amdgcn_mfma_f32_16x16x32_bf16(a, b1f, c2[1], 0, 0, 0);
        }
        const float cm0 = s_cmn[w * 32 + l15], cm1 = s_cmn[w * 32 + 16 + l15];
        #pragma unroll
        for (int reg = 0; reg < 4; ++reg) {
            const int row = q * 4 + reg;
            const float dd = s_dd[row * 16 + l15];
            s_log[row * LSTR + w * 32 + l15]      = SCALEF * (c2[0][reg] + cm0 + dd);
            s_log[row * LSTR + w * 32 + 16 + l15] = SCALEF * (c2[1][reg] + cm1 + dd);
        }
    }
    __syncthreads();   // B6

    // ---- P9: softmax over n per (r,m) ----
    if (t < 128) {
        const int r = t >> 3, m = t & 7;
        float* lg = &s_log[r * LSTR + m * 16];
        float mx = lg[0];
        #pragma unroll
        for (int n = 1; n < 16; ++n) mx = fmaxf(mx, lg[n]);
        float sum = 0.f, p[16];
        #pragma unroll
        for (int n = 0; n < 16; ++n) { p[n] = __expf(lg[n] - mx); sum += p[n]; }
        const float inv = 1.f / sum;
        #pragma unroll
        for (int n = 0; n < 16; ++n) lg[n] = p[n] * inv;
    }
    __syncthreads();   // B7

    // ---- P10: w_ot (into s_dd) + unnormalized w_rep ----
    {
        const int r = t >> 4;
        float wot = 0.f;
        #pragma unroll
        for (int m = 0; m < 8; ++m) wot += s_log[r * LSTR + m * 16 + (t & 15)];
        s_dd[t] = wot * 0.125f;
        s_wrep[t] = pw_pre * __expf(ETA0 * fit_pre);
    }
    __syncthreads();   // B8

    // ---- P11: blend -> w (in s_dd) ----
    if (t < ROWS) {
        float srep = 0.f;
        #pragma unroll
        for (int n = 0; n < 16; ++n) srep += s_wrep[t * 16 + n];
        const float irep = 1.f / (srep + 1e-8f);
        const float alpha = 0.06f + 0.24f * (1.f - s_crisis[t]);
        float wn[16], sw = 0.f;
        #pragma unroll
        for (int n = 0; n < 16; ++n) {
            wn[n] = alpha * s_dd[t * 16 + n] + (1.f - alpha) * s_wrep[t * 16 + n] * irep;
            sw += wn[n];
        }
        const float isw = 1.f / (sw + 1e-8f);
        #pragma unroll
        for (int n = 0; n < 16; ++n) s_dd[t * 16 + n] = wn[n] * isw;
    }
    __syncthreads();   // B9

    // ---- P12: mixed = w@conc + 1, softmax(30), write ----
    {
        const int r = w * 4 + q;
        const int a0 = l15;
        const int a1 = a0 + 16;
        const bool v1 = a1 < AA;
        float wreg[16];
        #pragma unroll
        for (int n = 0; n < 16; ++n) wreg[n] = s_dd[r * 16 + n];
        float m0 = 1.f, m1 = 1.f;
        const int a1s = v1 ? a1 : 0;
        #pragma unroll
        for (int n = 0; n < 16; ++n) {
            m0 = fmaf(wreg[n], s_conc[n * AA + a0], m0);
            m1 = fmaf(wreg[n], s_conc[n * AA + a1s], m1);
        }
        float mx = v1 ? fmaxf(m0, m1) : m0;
        #pragma unroll
        for (int off = 1; off < 16; off <<= 1) mx = fmaxf(mx, __shfl_xor(mx, off));
        float e0 = __expf(m0 - mx);
        float e1 = v1 ? __expf(m1 - mx) : 0.f;
        float se = e0 + e1;
        #pragma unroll
        for (int off = 1; off < 16; off <<= 1) se += __shfl_xor(se, off);
        const float inv = 1.f / se;
        out[(size_t)(row0 + r) * AA + a0] = e0 * inv;
        if (v1) out[(size_t)(row0 + r) * AA + a1] = e1 * inv;
    }
}

extern "C" void kernel_launch(void* const* d_in, const int* in_sizes, int n_in,
                              void* d_out, int out_size, void* d_ws, size_t ws_size,
                              hipStream_t stream) {
    const float* state   = (const float*)d_in[0];
    const float* fitness = (const float*)d_in[1];
    const float* proto   = (const float*)d_in[2];
    const float* enc_W1  = (const float*)d_in[3];
    const float* enc_b1  = (const float*)d_in[4];
    const float* ln_g    = (const float*)d_in[5];
    const float* ln_b    = (const float*)d_in[6];
    const float* enc_W2  = (const float*)d_in[7];
    const float* enc_b2  = (const float*)d_in[8];
    const float* dec_W1  = (const float*)d_in[9];
    const float* dec_b1  = (const float*)d_in[10];
    const float* dec_W2  = (const float*)d_in[11];
    const float* dec_b2  = (const float*)d_in[12];
    const float* tc_W    = (const float*)d_in[13];
    const float* tc_b    = (const float*)d_in[14];
    const float* tc_cW   = (const float*)d_in[15];
    const float* tc_cb   = (const float*)d_in[16];
    const float* w_prev  = (const float*)d_in[19];
    float* out = (float*)d_out;

    short* W1P = (short*)d_ws;              // 81920 shorts
    short* W3P = W1P + 81920;               // 32768
    short* PDP = W3P + 32768;               // 8192
    short* TCP = PDP + 8192;                // 8192
    float* cmn  = (float*)(TCP + 8192);     // 128
    float* conc = cmn + 128;                // 480

    pre_kernel<<<61, 256, 0, stream>>>(proto, enc_W1, enc_W2, enc_b2,
                                       tc_W, tc_cW,
                                       dec_W1, dec_b1, dec_W2, dec_b2,
                                       W1P, W3P, PDP, TCP, cmn, conc);
    main_kernel<<<NBATCH / ROWS, 256, 0, stream>>>(state, fitness,
                                                   enc_b1, ln_g, ln_b,
                                                   tc_b, tc_cb, w_prev,
                                                   W1P, W3P, PDP, TCP, cmn, conc, out);
}